// Round 2
// baseline (329.509 us; speedup 1.0000x reference)
//
#include <hip/hip_runtime.h>

typedef __attribute__((ext_vector_type(8))) short bf16x8;
typedef __attribute__((ext_vector_type(4))) float f32x4;

__device__ __forceinline__ unsigned short f2bf(float f) {
    union { float f; unsigned int u; } v; v.f = f;
    unsigned int u = v.u;
    return (unsigned short)((u + 0x7FFFu + ((u >> 16) & 1u)) >> 16);
}

__device__ __forceinline__ void cp16_g2l(const void* g, void* l) {
    __builtin_amdgcn_global_load_lds(
        (const __attribute__((address_space(1))) unsigned int*)g,
        (__attribute__((address_space(3))) unsigned int*)l, 16, 0, 0);
}

// ---- one-time: W_h f32 [128][384] -> bf16 "LDS image" (XOR-swizzled) in ws ----
__global__ __launch_bounds__(384) void k_cvtW(const float* __restrict__ Wh,
                                              unsigned short* __restrict__ Wbf) {
    int n = blockIdx.x, k = threadIdx.x;
    Wbf[n * 384 + (k ^ ((n & 7) << 3))] = f2bf(Wh[n * 384 + k]);
}

// ---------------- level kernel ----------------
// LEAF=1: children computed on the fly from contC (contents of level j+1 == 9).
// LEAF=0: children DMA'd from embIn, which is stored in "child-image" layout:
//   offset(row R, col n) = (R>>7)*16384 + (R&1)*8192 + ((R&127)>>1)*128 + (n ^ ((((R&127)>>1)&7)<<3))
template<int LEAF, int LAST>
__global__ __launch_bounds__(512) void k_level(
    const unsigned short* __restrict__ embIn,
    const float* __restrict__ contO,   // [n][8] own contents
    const float* __restrict__ contC,   // [2n][8] child contents (LEAF only)
    const unsigned short* __restrict__ Wbf, // swizzled bf16 W image [128*384]
    const float* __restrict__ Wu,      // [128][8]
    const float* __restrict__ bu,      // [128]
    const float* __restrict__ bh,      // [128]
    unsigned short* __restrict__ embOut, // child-image layout
    float* __restrict__ outF,          // row-major f32 (LAST)
    int n_nodes)
{
    // LDS: 32K (A) + 16K (u) + 96K (W) + 1K + 2K = 147.5 KiB -> 1 block/CU, 8 waves
    __shared__ __align__(16) unsigned short A_lds[2][64][128];
    __shared__ __align__(16) unsigned short u_lds[64][128];
    __shared__ __align__(16) unsigned short W_lds[128 * 384];
    __shared__ __align__(16) unsigned short cpO[64][8];
    __shared__ __align__(16) unsigned short cpC[128][8];

    int t = threadIdx.x, lane = t & 63, wid = t >> 6;       // 8 waves
    int wr = wid >> 1, wc = wid & 1;                        // wave tile: rows wr*16, cols wc*64
    int l15 = lane & 15, l4 = lane >> 4;

    // ---- W stage: pure linear DMA of the pre-swizzled image (6144 x 16B) ----
    for (int it = 0; it < 12; ++it) {
        int q = wid * 768 + it * 64 + lane;
        cp16_g2l(Wbf + q * 8, &W_lds[q * 8]);
    }

    // ---- register Wu/bu fragments (B-operand of the K=32 u-GEMM, zero-padded in regs) ----
    bf16x8 wuf[8];
    #pragma unroll
    for (int nf = 0; nf < 8; ++nf) {
        bf16x8 v = {0, 0, 0, 0, 0, 0, 0, 0};
        int n = nf * 16 + l15;
        if (l4 == 0) {
            #pragma unroll
            for (int k = 0; k < 8; ++k) ((unsigned short*)&v)[k] = f2bf(Wu[n * 8 + k]);
        } else if (l4 == 1) {
            ((unsigned short*)&v)[0] = f2bf(bu[n]);   // bias column (k=8), pairs with 1.0 in A
        }
        wuf[nf] = v;
    }
    float bhv[4];
    #pragma unroll
    for (int nf = 0; nf < 4; ++nf) bhv[nf] = bh[wc * 64 + nf * 16 + l15];

    bf16x8 onesA = {0, 0, 0, 0, 0, 0, 0, 0};
    ((unsigned short*)&onesA)[0] = 0x3F80;              // 1.0 at k=8

    int ntiles = n_nodes >> 6;
    for (int tile = blockIdx.x; tile < ntiles; tile += gridDim.x) {
        __syncthreads();  // prev tile's readers done (also drains W DMA on iter 0)

        if (!LEAF) {
            // A image: 2048 x 16B contiguous chunks, linear DMA
            const unsigned short* src = embIn + (size_t)tile * 16384;
            #pragma unroll
            for (int it = 0; it < 4; ++it) {
                int q = wid * 256 + it * 64 + lane;
                cp16_g2l(src + q * 8, &A_lds[0][0][0] + q * 8);
            }
        } else {
            // stage child contents (128 rows x 8)
            #pragma unroll
            for (int e = t; e < 1024; e += 512)
                cpC[e >> 3][e & 7] = f2bf(contC[(size_t)tile * 1024 + e]);
        }
        // own contents (64 rows x 8), one elem/thread
        cpO[t >> 3][t & 7] = f2bf(contO[(size_t)tile * 512 + t]);

        // barrier that drains LDS writes but NOT the A DMA (vmcnt) -> DMA overlaps u-phase
        asm volatile("s_waitcnt lgkmcnt(0)" ::: "memory");
        __builtin_amdgcn_s_barrier();
        __builtin_amdgcn_sched_barrier(0);

        if (LEAF) {
            // child-u: wave computes child rows wid*16..+15, all 128 cols
            bf16x8 ac = (l4 == 0) ? *(const bf16x8*)&cpC[wid * 16 + l15][0]
                      : (l4 == 1) ? onesA : (bf16x8){0, 0, 0, 0, 0, 0, 0, 0};
            #pragma unroll
            for (int nf = 0; nf < 8; ++nf) {
                f32x4 z = {0.f, 0.f, 0.f, 0.f};
                z = __builtin_amdgcn_mfma_f32_16x16x32_bf16(ac, wuf[nf], z, 0, 0, 0);
                #pragma unroll
                for (int r = 0; r < 4; ++r) {
                    int rr = wid * 16 + l4 * 4 + r;
                    int ii = rr >> 1, cc = rr & 1;
                    int nn = nf * 16 + l15;
                    A_lds[cc][ii][nn ^ ((ii & 7) << 3)] = f2bf(fmaxf(z[r], 0.f));
                }
            }
        }
        {
            // own-u: wave rows wr*16..+15, cols wc*64..+63
            bf16x8 au = (l4 == 0) ? *(const bf16x8*)&cpO[wr * 16 + l15][0]
                      : (l4 == 1) ? onesA : (bf16x8){0, 0, 0, 0, 0, 0, 0, 0};
            #pragma unroll
            for (int nf = 0; nf < 4; ++nf) {
                f32x4 z = {0.f, 0.f, 0.f, 0.f};
                z = __builtin_amdgcn_mfma_f32_16x16x32_bf16(au, wuf[wc * 4 + nf], z, 0, 0, 0);
                #pragma unroll
                for (int r = 0; r < 4; ++r) {
                    int iu = wr * 16 + l4 * 4 + r;
                    int nn = wc * 64 + nf * 16 + l15;
                    u_lds[iu][nn ^ ((iu & 7) << 3)] = f2bf(fmaxf(z[r], 0.f));
                }
            }
        }
        __syncthreads();  // drains A DMA (vmcnt) + u/A LDS writes

        // ---- main GEMM: K=384 = [child0 | child1 | u], acc init with bh ----
        f32x4 acc[4];
        #pragma unroll
        for (int nf = 0; nf < 4; ++nf) acc[nf] = (f32x4){bhv[nf], bhv[nf], bhv[nf], bhv[nf]};

        #pragma unroll
        for (int kb = 0; kb < 12; ++kb) {
            int i = wr * 16 + l15;
            const unsigned short* ap;
            if (kb < 8) ap = &A_lds[kb >> 2][i][((((kb & 3) * 4) + l4) ^ (i & 7)) * 8];
            else        ap = &u_lds[i][((((kb - 8) * 4) + l4) ^ (i & 7)) * 8];
            bf16x8 af = *(const bf16x8*)ap;
            #pragma unroll
            for (int nf = 0; nf < 4; ++nf) {
                int n = wc * 64 + nf * 16 + l15;
                bf16x8 bfr = *(const bf16x8*)&W_lds[n * 384 + ((kb * 4 + l4) ^ (n & 7)) * 8];
                acc[nf] = __builtin_amdgcn_mfma_f32_16x16x32_bf16(af, bfr, acc[nf], 0, 0, 0);
            }
        }

        // ---- epilogue: relu + store (child-image for next level, or f32 row-major) ----
        #pragma unroll
        for (int nf = 0; nf < 4; ++nf)
            #pragma unroll
            for (int r = 0; r < 4; ++r) {
                int iloc = wr * 16 + l4 * 4 + r;
                int n = wc * 64 + nf * 16 + l15;
                int R = tile * 64 + iloc;
                float v = fmaxf(acc[nf][r], 0.f);
                if (LAST) {
                    outF[(size_t)R * 128 + n] = v;
                } else {
                    int tp = R >> 7, rl = R & 127, cc = rl & 1, ii = rl >> 1;
                    embOut[(size_t)tp * 16384 + cc * 8192 + ii * 128 + (n ^ ((ii & 7) << 3))] = f2bf(v);
                }
            }
    }
}

extern "C" void kernel_launch(void* const* d_in, const int* in_sizes, int n_in,
                              void* d_out, int out_size, void* d_ws, size_t ws_size,
                              hipStream_t stream) {
    const float* contents[10];
    for (int j = 0; j < 10; ++j) contents[j] = (const float*)d_in[j];
    const float* Wu = (const float*)d_in[19];
    const float* bu = (const float*)d_in[20];
    const float* Wh = (const float*)d_in[21];
    const float* bh = (const float*)d_in[22];

    unsigned short* Wbf  = (unsigned short*)d_ws;                                   // 96 KiB
    unsigned short* bufE = (unsigned short*)((char*)d_ws + (1u << 20));             // 64 MiB (even levels)
    unsigned short* bufO = (unsigned short*)((char*)d_ws + (1u << 20) + (64u << 20)); // 32 MiB (odd levels)

    k_cvtW<<<128, 384, 0, stream>>>(Wh, Wbf);

    // level 8 (leaf-fused): children = relu(contents_9 @ Wu^T + bu) computed in-kernel
    k_level<1, 0><<<256, 512, 0, stream>>>(nullptr, contents[8], contents[9], Wbf,
                                           Wu, bu, bh, bufE, nullptr, 1024 << 8);
    // levels 7..1
    for (int j = 7; j >= 1; --j) {
        int n = 1024 << j;
        const unsigned short* in = (j & 1) ? bufE : bufO;  // emb_{j+1}
        unsigned short* outp     = (j & 1) ? bufO : bufE;  // emb_j
        int ntiles = n >> 6;
        int grid = ntiles < 256 ? ntiles : 256;
        k_level<0, 0><<<grid, 512, 0, stream>>>(in, contents[j], nullptr, Wbf,
                                                Wu, bu, bh, outp, nullptr, n);
    }
    // level 0 -> f32 output
    k_level<0, 1><<<16, 512, 0, stream>>>(bufO, contents[0], nullptr, Wbf,
                                          Wu, bu, bh, nullptr, (float*)d_out, 1024);
}

// Round 3
// 313.914 us; speedup vs baseline: 1.0497x; 1.0497x over previous
//
#include <hip/hip_runtime.h>

typedef __attribute__((ext_vector_type(8))) short bf16x8;
typedef __attribute__((ext_vector_type(4))) float f32x4;

__device__ __forceinline__ unsigned short f2bf(float f) {
    union { float f; unsigned int u; } v; v.f = f;
    unsigned int u = v.u;
    return (unsigned short)((u + 0x7FFFu + ((u >> 16) & 1u)) >> 16);
}

__device__ __forceinline__ void cp16_g2l(const void* g, void* l) {
    __builtin_amdgcn_global_load_lds(
        (const __attribute__((address_space(1))) unsigned int*)g,
        (__attribute__((address_space(3))) unsigned int*)l, 16, 0, 0);
}

// ---- one-time: W_h f32 [128][384] -> plain bf16 row-major image in ws ----
__global__ __launch_bounds__(384) void k_cvtW(const float* __restrict__ Wh,
                                              unsigned short* __restrict__ Wbf) {
    int n = blockIdx.x, k = threadIdx.x;
    Wbf[n * 384 + k] = f2bf(Wh[n * 384 + k]);
}

// ---------------- level kernel ----------------
// Block tile: 128 own rows x 128 cols. 8 waves, wave tile 64x32 (wr=wid>>2, wc=wid&3).
// W lives in registers (each wave holds its 32-col quarter: 24 bf16x8 = 96 VGPR).
// emb stored in "child-image" layout per 128-own-row consumer tile (256 child rows):
//   R: global child row. tc=R>>8, rr=R&255, cc=rr&1, il=rr>>1, slab=(il>>6)*2+cc, ii=il&63
//   elem offset = tc*32768 + (slab*64+ii)*128 + (n ^ ((ii&7)<<3))
template<int LEAF, int LAST>
__global__ __launch_bounds__(512, 2) void k_level(
    const unsigned short* __restrict__ embIn,
    const float* __restrict__ contO,   // [n][8] own contents
    const float* __restrict__ contC,   // [2n][8] child contents (LEAF only)
    const unsigned short* __restrict__ Wbf, // plain bf16 W image [128*384]
    const float* __restrict__ Wu,      // [128][8]
    const float* __restrict__ bu,      // [128]
    const float* __restrict__ bh,      // [128]
    unsigned short* __restrict__ embOut, // child-image layout
    float* __restrict__ outF,          // row-major f32 (LAST)
    int n_nodes)
{
    // LDS: 64K (A) + 32K (u) + 2K + 4K = 102 KiB -> 1 block/CU, 8 waves
    __shared__ __align__(16) unsigned short A_lds[4][64][128]; // [slab][ii][n^swz]
    __shared__ __align__(16) unsigned short u_lds[128][128];   // XOR-swz by row
    __shared__ __align__(16) unsigned short cpO[128][8];
    __shared__ __align__(16) unsigned short cpC[256][8];

    int t = threadIdx.x, lane = t & 63, wid = t >> 6;
    int wr = wid >> 2, wc = wid & 3;     // wave tile: rows wr*64..+64, cols wc*32..+32
    int l15 = lane & 15, l4 = lane >> 4;

    // ---- persistent W fragments: n = wc*32 + nf2*16 + l15, k = kb*32 + l4*8 + e ----
    bf16x8 wreg[2][12];
    #pragma unroll
    for (int nf2 = 0; nf2 < 2; ++nf2) {
        int n = wc * 32 + nf2 * 16 + l15;
        #pragma unroll
        for (int kb = 0; kb < 12; ++kb)
            wreg[nf2][kb] = *reinterpret_cast<const bf16x8*>(Wbf + n * 384 + kb * 32 + l4 * 8);
    }

    // ---- register Wu/bu fragments (B-op of the K=32-padded u-GEMM) ----
    bf16x8 wuf[8];
    #pragma unroll
    for (int nf = 0; nf < 8; ++nf) {
        bf16x8 v = {0, 0, 0, 0, 0, 0, 0, 0};
        int n = nf * 16 + l15;
        if (l4 == 0) {
            #pragma unroll
            for (int k = 0; k < 8; ++k) ((unsigned short*)&v)[k] = f2bf(Wu[n * 8 + k]);
        } else if (l4 == 1) {
            ((unsigned short*)&v)[0] = f2bf(bu[n]);   // bias column (k=8)
        }
        wuf[nf] = v;
    }
    float bhv[2];
    #pragma unroll
    for (int nf2 = 0; nf2 < 2; ++nf2) bhv[nf2] = bh[wc * 32 + nf2 * 16 + l15];

    bf16x8 onesA = {0, 0, 0, 0, 0, 0, 0, 0};
    ((unsigned short*)&onesA)[0] = 0x3F80;            // 1.0 at k=8
    const bf16x8 zeroA = {0, 0, 0, 0, 0, 0, 0, 0};

    int ntiles = n_nodes >> 7;
    for (int tile = blockIdx.x; tile < ntiles; tile += gridDim.x) {
        __syncthreads();  // prev tile's readers done

        if (!LEAF) {
            // A image: 4096 x 16B contiguous chunks, linear DMA (64 KiB)
            const unsigned short* src = embIn + (size_t)tile * 32768;
            #pragma unroll
            for (int it = 0; it < 8; ++it) {
                int q = t + it * 512;
                cp16_g2l(src + q * 8, &A_lds[0][0][0] + q * 8);
            }
        } else {
            // child contents: 256 rows x 8
            #pragma unroll
            for (int it = 0; it < 4; ++it) {
                int e = t + it * 512;
                cpC[e >> 3][e & 7] = f2bf(contC[(size_t)tile * 2048 + e]);
            }
        }
        // own contents: 128 rows x 8
        #pragma unroll
        for (int it = 0; it < 2; ++it) {
            int e = t + it * 512;
            cpO[e >> 3][e & 7] = f2bf(contO[(size_t)tile * 1024 + e]);
        }

        // barrier draining LDS writes but NOT the A DMA (vmcnt) -> DMA overlaps u-phase
        asm volatile("s_waitcnt lgkmcnt(0)" ::: "memory");
        __builtin_amdgcn_s_barrier();
        __builtin_amdgcn_sched_barrier(0);

        if (LEAF) {
            // child-u: wave computes child rows wid*32..+31, all 128 cols, into A image
            #pragma unroll
            for (int rb = 0; rb < 2; ++rb) {
                bf16x8 ac = (l4 == 0) ? *(const bf16x8*)&cpC[wid * 32 + rb * 16 + l15][0]
                          : (l4 == 1) ? onesA : zeroA;
                #pragma unroll
                for (int nf = 0; nf < 8; ++nf) {
                    f32x4 z = {0.f, 0.f, 0.f, 0.f};
                    z = __builtin_amdgcn_mfma_f32_16x16x32_bf16(ac, wuf[nf], z, 0, 0, 0);
                    #pragma unroll
                    for (int r = 0; r < 4; ++r) {
                        int rr = wid * 32 + rb * 16 + l4 * 4 + r;
                        int cc = rr & 1, il = rr >> 1;
                        int slab = (il >> 6) * 2 + cc, ii = il & 63;
                        int n = nf * 16 + l15;
                        A_lds[slab][ii][n ^ ((ii & 7) << 3)] = f2bf(fmaxf(z[r], 0.f));
                    }
                }
            }
        }
        {
            // own-u: wave rows wid*16..+15, all 128 cols
            bf16x8 au = (l4 == 0) ? *(const bf16x8*)&cpO[wid * 16 + l15][0]
                      : (l4 == 1) ? onesA : zeroA;
            #pragma unroll
            for (int nf = 0; nf < 8; ++nf) {
                f32x4 z = {0.f, 0.f, 0.f, 0.f};
                z = __builtin_amdgcn_mfma_f32_16x16x32_bf16(au, wuf[nf], z, 0, 0, 0);
                #pragma unroll
                for (int r = 0; r < 4; ++r) {
                    int iu = wid * 16 + l4 * 4 + r;
                    int n = nf * 16 + l15;
                    u_lds[iu][n ^ ((iu & 7) << 3)] = f2bf(fmaxf(z[r], 0.f));
                }
            }
        }
        __syncthreads();  // drains A DMA (vmcnt) + u/A LDS writes

        // ---- main GEMM: K=384 = [child0 | child1 | u], B entirely from registers ----
        f32x4 acc[4][2];
        #pragma unroll
        for (int mf = 0; mf < 4; ++mf)
            #pragma unroll
            for (int nf2 = 0; nf2 < 2; ++nf2)
                acc[mf][nf2] = (f32x4){bhv[nf2], bhv[nf2], bhv[nf2], bhv[nf2]};

        #pragma unroll
        for (int kb = 0; kb < 12; ++kb) {
            bf16x8 af[4];
            #pragma unroll
            for (int mf = 0; mf < 4; ++mf) {
                int i = wr * 64 + mf * 16 + l15;
                const unsigned short* ap;
                if (kb < 8) {
                    int slab = (i >> 6) * 2 + (kb >> 2), ii = i & 63;
                    int c16 = (((kb & 3) * 4) + l4) ^ (ii & 7);
                    ap = &A_lds[slab][ii][c16 * 8];
                } else {
                    int c16 = (((kb - 8) * 4) + l4) ^ (i & 7);
                    ap = &u_lds[i][c16 * 8];
                }
                af[mf] = *(const bf16x8*)ap;
            }
            #pragma unroll
            for (int mf = 0; mf < 4; ++mf)
                #pragma unroll
                for (int nf2 = 0; nf2 < 2; ++nf2)
                    acc[mf][nf2] = __builtin_amdgcn_mfma_f32_16x16x32_bf16(af[mf], wreg[nf2][kb], acc[mf][nf2], 0, 0, 0);
        }

        // ---- epilogue: relu + store (child-image for next level, or f32 row-major) ----
        #pragma unroll
        for (int mf = 0; mf < 4; ++mf)
            #pragma unroll
            for (int nf2 = 0; nf2 < 2; ++nf2)
                #pragma unroll
                for (int r = 0; r < 4; ++r) {
                    int i = wr * 64 + mf * 16 + l4 * 4 + r;
                    int n = wc * 32 + nf2 * 16 + l15;
                    int R = tile * 128 + i;
                    float v = fmaxf(acc[mf][nf2][r], 0.f);
                    if (LAST) {
                        outF[(size_t)R * 128 + n] = v;
                    } else {
                        int tc = R >> 8, rr = R & 255;
                        int cc = rr & 1, il = rr >> 1;
                        int slab = (il >> 6) * 2 + cc, ii = il & 63;
                        embOut[(size_t)tc * 32768 + (slab * 64 + ii) * 128 + (n ^ ((ii & 7) << 3))] = f2bf(v);
                    }
                }
    }
}

extern "C" void kernel_launch(void* const* d_in, const int* in_sizes, int n_in,
                              void* d_out, int out_size, void* d_ws, size_t ws_size,
                              hipStream_t stream) {
    const float* contents[10];
    for (int j = 0; j < 10; ++j) contents[j] = (const float*)d_in[j];
    const float* Wu = (const float*)d_in[19];
    const float* bu = (const float*)d_in[20];
    const float* Wh = (const float*)d_in[21];
    const float* bh = (const float*)d_in[22];

    unsigned short* Wbf  = (unsigned short*)d_ws;                                     // 96 KiB
    unsigned short* bufE = (unsigned short*)((char*)d_ws + (1u << 20));               // 64 MiB (even levels)
    unsigned short* bufO = (unsigned short*)((char*)d_ws + (1u << 20) + (64u << 20)); // 32 MiB (odd levels)

    k_cvtW<<<128, 384, 0, stream>>>(Wh, Wbf);

    // level 8 (leaf-fused): children = relu(contents_9 @ Wu^T + bu) computed in-kernel
    k_level<1, 0><<<256, 512, 0, stream>>>(nullptr, contents[8], contents[9], Wbf,
                                           Wu, bu, bh, bufE, nullptr, 1024 << 8);
    // levels 7..1
    for (int j = 7; j >= 1; --j) {
        int n = 1024 << j;
        const unsigned short* in = (j & 1) ? bufE : bufO;  // emb_{j+1}
        unsigned short* outp     = (j & 1) ? bufO : bufE;  // emb_j
        int ntiles = n >> 7;
        int grid = ntiles < 256 ? ntiles : 256;
        k_level<0, 0><<<grid, 512, 0, stream>>>(in, contents[j], nullptr, Wbf,
                                                Wu, bu, bh, outp, nullptr, n);
    }
    // level 0 -> f32 output (8 tiles)
    k_level<0, 1><<<8, 512, 0, stream>>>(bufO, contents[0], nullptr, Wbf,
                                         Wu, bu, bh, nullptr, (float*)d_out, 1024);
}